// Round 7
// baseline (181.468 us; speedup 1.0000x reference)
//
#include <hip/hip_runtime.h>
#include <hip/hip_bf16.h>

#define NB 2
#define NN 512
#define ND 256
#define NH 256
#define NH2 128
#define JT 32

typedef __bf16 bf16x8 __attribute__((ext_vector_type(8)));
typedef __bf16 bf16x4 __attribute__((ext_vector_type(4)));
typedef float f32x4 __attribute__((ext_vector_type(4)));

__device__ __forceinline__ float bflo(unsigned d) { return __uint_as_float(d << 16); }
__device__ __forceinline__ float bfhi(unsigned d) { return __uint_as_float(d & 0xffff0000u); }

__device__ __forceinline__ void buildHs(char* dst, const uint4* rg4, const float* l8,
                                        unsigned hsOff) {
  #pragma unroll
  for (int it = 0; it < 4; ++it) {
    const uint4 rv = rg4[it];
    bf16x8 hb;
    #pragma unroll
    for (int e = 0; e < 4; ++e) {
      const unsigned d = ((const unsigned*)&rv)[e];
      float t0 = bflo(d) + l8[2 * e];
      float t1 = bfhi(d) + l8[2 * e + 1];
      t0 = t0 > 0.f ? t0 : 0.f;
      t1 = t1 > 0.f ? t1 : 0.f;
      hb[2 * e] = (__bf16)t0;
      hb[2 * e + 1] = (__bf16)t1;
    }
    *(bf16x8*)(dst + hsOff + it * 4096) = hb;
  }
}

// prep: 512 blocks x 2 rows. Outputs Lb (f32), Rb16 (bf16), XWt (bf16, [b][h][j]),
// W2b (bf16 transposed). W2 conversion folded in (64 elems/block).
__global__ __launch_bounds__(256) void prep_kernel(
    const float* __restrict__ x, const float* __restrict__ W1,
    const float* __restrict__ b1, const float* __restrict__ Wg,
    const float* __restrict__ bg, const float* __restrict__ W2,
    float* __restrict__ Lb, __bf16* __restrict__ Rb16,
    __bf16* __restrict__ XWt, __bf16* __restrict__ W2b) {
  const int blk = blockIdx.x;
  const int tid = threadIdx.x;
  __shared__ float xs[2][ND];
  __shared__ __align__(16) f32x4 part[4 * 384];   // [dg][(r*3+m)*64+hq] : 24KB
  const int r0 = blk * 2;
  xs[0][tid] = x[r0 * ND + tid];
  xs[1][tid] = x[(r0 + 1) * ND + tid];
  if (tid < 64) {   // W2 -> bf16 transposed, 64 elems/block
    const int idx = blk * 64 + tid;
    const int hh = idx >> 7, kk = idx & 127;
    W2b[kk * NH + hh] = (__bf16)W2[idx];
  }
  __syncthreads();

  const int dg = tid >> 6;     // d-quarter
  const int hq = tid & 63;     // h-quad
  f32x4 acc[2][3];
  #pragma unroll
  for (int r = 0; r < 2; ++r)
    #pragma unroll
    for (int m = 0; m < 3; ++m) acc[r][m] = (f32x4){0.f, 0.f, 0.f, 0.f};

  const int d0 = dg * 64;
  #pragma unroll 4
  for (int it = 0; it < 64; ++it) {
    const int d = d0 + it;
    const f32x4 wl = *(const f32x4*)(W1 + d * NH + hq * 4);
    const f32x4 wr = *(const f32x4*)(W1 + (ND + d) * NH + hq * 4);
    const f32x4 wg = *(const f32x4*)(Wg + d * NH + hq * 4);
    const float x0 = xs[0][d], x1 = xs[1][d];
    acc[0][0] += x0 * wl;  acc[0][1] += x0 * wr;  acc[0][2] += x0 * wg;
    acc[1][0] += x1 * wl;  acc[1][1] += x1 * wr;  acc[1][2] += x1 * wg;
  }
  #pragma unroll
  for (int r = 0; r < 2; ++r)
    #pragma unroll
    for (int m = 0; m < 3; ++m)
      part[dg * 384 + (r * 3 + m) * 64 + hq] = acc[r][m];
  __syncthreads();

  for (int s = tid; s < 384; s += 256) {
    f32x4 sum = part[s] + part[384 + s] + part[768 + s] + part[1152 + s];
    const int r = s / 192;
    const int rem = s - r * 192;
    const int m = rem >> 6;
    const int h = (rem & 63) * 4;
    const int row = r0 + r;
    if (m == 0) {
      const f32x4 bv = *(const f32x4*)(b1 + h);
      *(f32x4*)(Lb + row * NH + h) = sum + bv;
    } else if (m == 1) {
      bf16x4 o;
      #pragma unroll
      for (int e = 0; e < 4; ++e) o[e] = (__bf16)sum[e];
      *(bf16x4*)(Rb16 + row * NH + h) = o;
    } else {
      const f32x4 v = sum + *(const f32x4*)(bg + h);
      const int bb = row >> 9, jj = row & (NN - 1);
      #pragma unroll
      for (int e = 0; e < 4; ++e)
        XWt[bb * (NH * NN) + (h + e) * NN + jj] = (__bf16)v[e];
    }
  }
}

// edge: one block per (b,i). 4 blocks/CU. SINGLE barrier per iteration:
// [sigmoid(jt-1) wave0] | issue rg4(jt+1) | MFMA Hs[buf] | epilogue->red[buf] |
// buildHs(rg4 -> Hs[buf^1]) | barrier.  Loads issued at top are consumed before
// the barrier -> the compiler's forced vmcnt(0) drain at s_barrier is empty.
__global__ __launch_bounds__(256, 4) void edge_kernel(
    const float* __restrict__ base_adj,
    const float* __restrict__ b2, const float* __restrict__ W3,
    const float* __restrict__ b3, const float* __restrict__ Lb,
    const __bf16* __restrict__ Rb16, const __bf16* __restrict__ XWt,
    const __bf16* __restrict__ W2b, float* __restrict__ out) {
  __shared__ __align__(16) char HsB[32768];     // Hs double buffer 2x16KB
  __shared__ __align__(16) float adjs[NN];
  __shared__ __align__(16) float ew[NN];        // later overlaid by ewhi/ewlo (bf16)
  __shared__ float red[2][4][JT];               // double-buffered partials
  __shared__ float b2s[NH2], W3s[NH2];
  __shared__ float sred[8];

  const int blk = blockIdx.x;
  const int tid = threadIdx.x;
  const int lane = tid & 63;
  const int w = tid >> 6;        // wave id = k-quarter
  const int lr = lane & 15;
  const int lg = lane >> 4;
  const int b = blk >> 9;
  const int i = blk & (NN - 1);

  const __bf16* Rbb = Rb16 + b * NN * NH;
  const __bf16* XWtb = XWt + b * NH * NN;

  adjs[tid] = base_adj[(b * NN + i) * NN + tid];
  adjs[tid + 256] = base_adj[(b * NN + i) * NN + tid + 256];
  if (tid < NH2) { b2s[tid] = b2[tid]; W3s[tid] = W3[tid]; }
  const float b3v = b3[0];

  // W2 fragments: wave w covers k in [w*32, w*32+32)
  bf16x8 bfr[8][2];
  #pragma unroll
  for (int ks8 = 0; ks8 < 8; ++ks8)
    #pragma unroll
    for (int kb = 0; kb < 2; ++kb)
      bfr[ks8][kb] = *(const bf16x8*)(W2b + (w * 32 + kb * 16 + lr) * NH + ks8 * 32 + lg * 8);

  // per-thread loop-invariant L slice, straight from global (L2, broadcast)
  const int cth = tid & 31;
  const int rowth = tid >> 5;
  float l8[8];
  {
    const f32x4 la = *(const f32x4*)(Lb + blk * NH + cth * 8);
    const f32x4 lc = *(const f32x4*)(Lb + blk * NH + cth * 8 + 4);
    #pragma unroll
    for (int e = 0; e < 4; ++e) { l8[e] = la[e]; l8[4 + e] = lc[e]; }
  }
  const unsigned hsAddr0 = rowth * 512 + ((cth ^ (rowth & 7)) << 4);   // bytes

  // prologue: build tile 0 into Hs[0]
  uint4 rg4[4];
  #pragma unroll
  for (int it = 0; it < 4; ++it)
    rg4[it] = *(const uint4*)(Rbb + (it * 8 + rowth) * NH + cth * 8);
  buildHs(HsB, rg4, l8, hsAddr0);
  __syncthreads();

  for (int jt = 0; jt < 16; ++jt) {
    const int buf = jt & 1;
    // issue next tile's loads first (latency hidden under MFMA+epilogue)
    if (jt < 15) {
      #pragma unroll
      for (int it = 0; it < 4; ++it)
        rg4[it] = *(const uint4*)(Rbb + ((jt + 1) * JT + it * 8 + rowth) * NH + cth * 8);
    }
    // sigmoid for previous tile (wave 0 halves only, off critical path)
    if (jt > 0 && tid < JT) {
      const int pb = (jt - 1) & 1;
      const float v = red[pb][0][tid] + red[pb][1][tid] + red[pb][2][tid] +
                      red[pb][3][tid] + b3v;
      const float sg = 1.f / (1.f + __expf(-v));
      const int j = (jt - 1) * JT + tid;
      ew[j] = adjs[j] * sg + ((j == i) ? 1.f : 0.f);
    }

    // ---- MFMA: wave computes 32j x 32k on Hs[buf] ----
    const char* Hp = HsB + buf * 16384;
    f32x4 acc[2][2];
    #pragma unroll
    for (int ja = 0; ja < 2; ++ja)
      #pragma unroll
      for (int kb = 0; kb < 2; ++kb) acc[ja][kb] = (f32x4){0.f, 0.f, 0.f, 0.f};
    #pragma unroll
    for (int ks8 = 0; ks8 < 8; ++ks8) {
      bf16x8 af[2];
      #pragma unroll
      for (int ja = 0; ja < 2; ++ja)
        af[ja] = *(const bf16x8*)(Hp + (ja * 16 + lr) * 512 + (((ks8 * 4 + lg) ^ (lr & 7)) << 4));
      #pragma unroll
      for (int ja = 0; ja < 2; ++ja)
        #pragma unroll
        for (int kb = 0; kb < 2; ++kb)
          acc[ja][kb] = __builtin_amdgcn_mfma_f32_16x16x32_bf16(af[ja], bfr[ks8][kb], acc[ja][kb], 0, 0, 0);
    }

    // ---- epilogue: relu(T+b2).W3 partial sums -> red[buf] ----
    #pragma unroll
    for (int ja = 0; ja < 2; ++ja) {
      #pragma unroll
      for (int r = 0; r < 4; ++r) {
        const int k0 = w * 32 + lr;
        float t0 = acc[ja][0][r] + b2s[k0];
        float t1 = acc[ja][1][r] + b2s[k0 + 16];
        t0 = t0 > 0.f ? t0 : 0.f;
        t1 = t1 > 0.f ? t1 : 0.f;
        float s = fmaf(t0, W3s[k0], t1 * W3s[k0 + 16]);
        s += __shfl_xor(s, 1, 16);
        s += __shfl_xor(s, 2, 16);
        s += __shfl_xor(s, 4, 16);
        s += __shfl_xor(s, 8, 16);
        if (lr == 0) red[buf][w][ja * 16 + lg * 4 + r] = s;
      }
    }

    // ---- build next Hs tile from rg4 (consumes the loads pre-barrier) ----
    if (jt < 15) buildHs(HsB + (buf ^ 1) * 16384, rg4, l8, hsAddr0);
    __syncthreads();
  }

  // final sigmoid (tile 15; red[1] complete after last barrier)
  if (tid < JT) {
    const float v = red[1][0][tid] + red[1][1][tid] + red[1][2][tid] +
                    red[1][3][tid] + b3v;
    const float sg = 1.f / (1.f + __expf(-v));
    const int j = 15 * JT + tid;
    ew[j] = adjs[j] * sg + ((j == i) ? 1.f : 0.f);
  }
  __syncthreads();

  // ---- softmax over ew[0..511] ----
  float v0 = ew[tid], v1 = ew[tid + 256];
  float m = fmaxf(v0, v1);
  #pragma unroll
  for (int off = 1; off < 64; off <<= 1) m = fmaxf(m, __shfl_xor(m, off, 64));
  if (lane == 0) sred[w] = m;
  __syncthreads();
  m = fmaxf(fmaxf(sred[0], sred[1]), fmaxf(sred[2], sred[3]));
  const float e0 = __expf(v0 - m), e1 = __expf(v1 - m);
  float ssum = e0 + e1;
  #pragma unroll
  for (int off = 1; off < 64; off <<= 1) ssum += __shfl_xor(ssum, off, 64);
  if (lane == 0) sred[4 + w] = ssum;
  __syncthreads();
  const float inv = 1.f / (sred[4] + sred[5] + sred[6] + sred[7]);
  const float p0 = e0 * inv, p1 = e1 * inv;

  // split p into bf16 hi+lo, overlaid on ew region (p = hi + lo exactly)
  __bf16* ewh = (__bf16*)ew;      // [512] hi at bytes [0,1024)
  __bf16* ewl = ewh + NN;         // [512] lo at bytes [1024,2048)
  {
    const __bf16 h0 = (__bf16)p0;
    const __bf16 h1 = (__bf16)p1;
    ewh[tid] = h0;        ewl[tid] = (__bf16)(p0 - (float)h0);
    ewh[tid + 256] = h1;  ewl[tid + 256] = (__bf16)(p1 - (float)h1);
  }
  __syncthreads();

  // PV via MFMA: A row0 = p_hi, row1 = p_lo, rows 2-15 = 0; B = XWt slices.
  const char* ewb = (const char*)ew;
  const unsigned aoff = (lr == 1 ? 1024u : 0u) + lg * 16;
  const bool azero = (lr >= 2);
  f32x4 pacc[4];
  #pragma unroll
  for (int q = 0; q < 4; ++q) pacc[q] = (f32x4){0.f, 0.f, 0.f, 0.f};
  #pragma unroll
  for (int ks = 0; ks < 16; ++ks) {
    uint4 pa = *(const uint4*)(ewb + aoff + ks * 64);
    if (azero) { pa.x = 0; pa.y = 0; pa.z = 0; pa.w = 0; }
    const bf16x8 paf = __builtin_bit_cast(bf16x8, pa);
    #pragma unroll
    for (int q = 0; q < 4; ++q) {
      const int h = w * 64 + q * 16 + lr;
      const bf16x8 bv = *(const bf16x8*)(XWtb + h * NN + ks * 32 + lg * 8);
      pacc[q] = __builtin_amdgcn_mfma_f32_16x16x32_bf16(paf, bv, pacc[q], 0, 0, 0);
    }
  }
  if (lg == 0) {
    #pragma unroll
    for (int q = 0; q < 4; ++q)
      out[blk * NH + w * 64 + q * 16 + lr] = pacc[q][0] + pacc[q][1];
  }
}

extern "C" void kernel_launch(void* const* d_in, const int* in_sizes, int n_in,
                              void* d_out, int out_size, void* d_ws, size_t ws_size,
                              hipStream_t stream) {
  const float* x        = (const float*)d_in[0];
  const float* base_adj = (const float*)d_in[1];
  const float* W1       = (const float*)d_in[2];
  const float* b1       = (const float*)d_in[3];
  const float* W2       = (const float*)d_in[4];
  const float* b2       = (const float*)d_in[5];
  const float* W3       = (const float*)d_in[6];
  const float* b3       = (const float*)d_in[7];
  const float* Wg       = (const float*)d_in[8];
  const float* bg       = (const float*)d_in[9];

  float*  Lb    = (float*)d_ws;                       // [1024,256] f32
  __bf16* Rb16  = (__bf16*)(Lb + NB * NN * NH);       // [1024,256] bf16
  __bf16* XWt   = Rb16 + NB * NN * NH;                // [B][256 h][512 j] bf16
  __bf16* W2b   = XWt + NB * NH * NN;                 // [128,256] bf16
  float* outp = (float*)d_out;

  prep_kernel<<<512, 256, 0, stream>>>(x, W1, b1, Wg, bg, W2, Lb, Rb16, XWt, W2b);
  edge_kernel<<<NB * NN, 256, 0, stream>>>(base_adj, b2, W3, b3, Lb, Rb16, XWt, W2b, outp);
}

// Round 8
// 175.869 us; speedup vs baseline: 1.0318x; 1.0318x over previous
//
#include <hip/hip_runtime.h>
#include <hip/hip_bf16.h>

#define NB 2
#define NN 512
#define ND 256
#define NH 256
#define NH2 128
#define JT 32

typedef __bf16 bf16x8 __attribute__((ext_vector_type(8)));
typedef __bf16 bf16x4 __attribute__((ext_vector_type(4)));
typedef __bf16 bf16x2 __attribute__((ext_vector_type(2)));
typedef float f32x4 __attribute__((ext_vector_type(4)));

__device__ __forceinline__ void gload_lds16(const void* g, void* l) {
  __builtin_amdgcn_global_load_lds((const __attribute__((address_space(1))) unsigned int*)g,
                                   (__attribute__((address_space(3))) unsigned int*)l, 16, 0, 0);
}
__device__ __forceinline__ float bflo(unsigned d) { return __uint_as_float(d << 16); }
__device__ __forceinline__ float bfhi(unsigned d) { return __uint_as_float(d & 0xffff0000u); }

// prep v2: 384 blocks = 16 row-groups (64 rows) x 24 col-groups (32 cols of the
// 768 concatenated L|R|G output columns). x staged in LDS once per block; W
// traffic = 16x3MB, x traffic = 24x1MB (~72MB total vs 1.5GB in v1).
// W2 -> bf16 transposed handled by blocks 0..127.
__global__ __launch_bounds__(256) void prep_kernel(
    const float* __restrict__ x, const float* __restrict__ W1,
    const float* __restrict__ b1, const float* __restrict__ Wg,
    const float* __restrict__ bg, const float* __restrict__ W2,
    float* __restrict__ Lb, __bf16* __restrict__ Rb16,
    __bf16* __restrict__ XWt, __bf16* __restrict__ W2b) {
  __shared__ __align__(16) float xs[64 * 260];   // 64 rows, pad 260 (bank spread)
  const int blk = blockIdx.x;
  const int tid = threadIdx.x;
  if (blk < 128) {   // W2 transpose-convert: 128*256 = 32768 elems
    const int idx = blk * 256 + tid;
    const int hh = idx >> 7, kk = idx & 127;
    W2b[kk * NH + hh] = (__bf16)W2[idx];
  }
  const int rg = blk / 24;
  const int cg = blk - rg * 24;
  const int r0 = rg * 64;
  const int m = cg >> 3;               // 0:L 1:R 2:G
  const int h0 = (cg & 7) * 32;
  const float* Wbase = (m == 2 ? Wg : W1 + (m == 1 ? 256 * NH : 0)) + h0;

  #pragma unroll
  for (int k = 0; k < 16; ++k) {
    const int q = k * 256 + tid;
    const int row = q >> 6, c4 = (q & 63) << 2;
    *(f32x4*)(xs + row * 260 + c4) = *(const f32x4*)(x + (r0 + row) * ND + c4);
  }
  __syncthreads();

  const int cs = tid & 15;             // cols 2cs, 2cs+1
  const int rs = tid >> 4;             // rows rs + 16*{0,1,2,3}
  const float* Wc = Wbase + 2 * cs;
  float2 acc[4];
  #pragma unroll
  for (int mm = 0; mm < 4; ++mm) { acc[mm].x = 0.f; acc[mm].y = 0.f; }

  for (int d4 = 0; d4 < 64; ++d4) {
    f32x4 xv[4];
    #pragma unroll
    for (int mm = 0; mm < 4; ++mm)
      xv[mm] = *(const f32x4*)(xs + (rs + 16 * mm) * 260 + d4 * 4);
    #pragma unroll
    for (int e = 0; e < 4; ++e) {
      const float2 wv = *(const float2*)(Wc + (d4 * 4 + e) * NH);
      #pragma unroll
      for (int mm = 0; mm < 4; ++mm) {
        acc[mm].x = fmaf(xv[mm][e], wv.x, acc[mm].x);
        acc[mm].y = fmaf(xv[mm][e], wv.y, acc[mm].y);
      }
    }
  }

  const int h = h0 + 2 * cs;
  if (m == 0) {
    const float2 bv = *(const float2*)(b1 + h);
    #pragma unroll
    for (int mm = 0; mm < 4; ++mm) {
      const int row = r0 + rs + 16 * mm;
      float2 o; o.x = acc[mm].x + bv.x; o.y = acc[mm].y + bv.y;
      *(float2*)(Lb + row * NH + h) = o;
    }
  } else if (m == 1) {
    #pragma unroll
    for (int mm = 0; mm < 4; ++mm) {
      const int row = r0 + rs + 16 * mm;
      bf16x2 o; o[0] = (__bf16)acc[mm].x; o[1] = (__bf16)acc[mm].y;
      *(bf16x2*)(Rb16 + row * NH + h) = o;
    }
  } else {
    const float2 bv = *(const float2*)(bg + h);
    #pragma unroll
    for (int mm = 0; mm < 4; ++mm) {
      const int row = r0 + rs + 16 * mm;
      const int bb = row >> 9, jj = row & (NN - 1);
      XWt[bb * (NH * NN) + h * NN + jj] = (__bf16)(acc[mm].x + bv.x);
      XWt[bb * (NH * NN) + (h + 1) * NN + jj] = (__bf16)(acc[mm].y + bv.y);
    }
  }
}

// edge: one block per (b,i). 4 blocks/CU. R3-proven loop (gload_lds staging,
// 2 barriers/jt, NO setprio). Tail: softmax + PV via MFMA (verified R6).
__global__ __launch_bounds__(256, 4) void edge_kernel(
    const float* __restrict__ base_adj,
    const float* __restrict__ b2, const float* __restrict__ W3,
    const float* __restrict__ b3, const float* __restrict__ Lb,
    const __bf16* __restrict__ Rb16, const __bf16* __restrict__ XWt,
    const __bf16* __restrict__ W2b, float* __restrict__ out) {
  __shared__ __align__(16) __bf16 Rs[JT * NH];   // 16KB, linear (gload_lds dest)
  __shared__ __align__(16) __bf16 Hs[JT * NH];   // 16KB, chunk^(row&7) swizzle
  __shared__ __align__(16) float Lbs[NH];
  __shared__ __align__(16) float adjs[NN];
  __shared__ __align__(16) float ew[NN];         // later overlaid by ewhi/ewlo (bf16)
  __shared__ float red[4][JT];
  __shared__ float b2s[NH2], W3s[NH2];
  __shared__ float sred[8];

  const int blk = blockIdx.x;
  const int tid = threadIdx.x;
  const int lane = tid & 63;
  const int w = tid >> 6;        // wave id = k-quarter
  const int lr = lane & 15;
  const int lg = lane >> 4;
  const int b = blk >> 9;
  const int i = blk & (NN - 1);

  const __bf16* Rbb = Rb16 + b * NN * NH;
  const __bf16* XWtb = XWt + b * NH * NN;

  // prologue staging (jt=0): 4 issues/wave of 1KB
  {
    const int laneoff = (lane >> 5) * NH + (lane & 31) * 8;
    #pragma unroll
    for (int q = 0; q < 4; ++q) {
      const __bf16* src = Rbb + (w * 4 + q) * 2 * NH + laneoff;
      gload_lds16(src, (char*)Rs + (w * 4 + q) * 1024);
    }
  }
  // W2 fragments: wave w covers k in [w*32, w*32+32)
  bf16x8 bfr[8][2];
  #pragma unroll
  for (int ks8 = 0; ks8 < 8; ++ks8)
    #pragma unroll
    for (int kb = 0; kb < 2; ++kb)
      bfr[ks8][kb] = *(const bf16x8*)(W2b + (w * 32 + kb * 16 + lr) * NH + ks8 * 32 + lg * 8);

  Lbs[tid] = Lb[blk * NH + tid];
  adjs[tid] = base_adj[(b * NN + i) * NN + tid];
  adjs[tid + 256] = base_adj[(b * NN + i) * NN + tid + 256];
  if (tid < NH2) { b2s[tid] = b2[tid]; W3s[tid] = W3[tid]; }
  const float b3v = b3[0];
  asm volatile("s_waitcnt vmcnt(0)" ::: "memory");
  __syncthreads();

  // per-thread loop-invariant L slice
  const int cth = tid & 31;
  const int rowth = tid >> 5;
  float l8[8];
  #pragma unroll
  for (int e = 0; e < 8; ++e) l8[e] = Lbs[cth * 8 + e];
  const unsigned rsAddr0 = tid * 16;                                   // bytes
  const unsigned hsAddr0 = rowth * 512 + ((cth ^ (rowth & 7)) << 4);   // bytes

  for (int jt = 0; jt < 16; ++jt) {
    // ---- build Hs = bf16(relu(L + R)) from Rs ----
    #pragma unroll
    for (int it = 0; it < 4; ++it) {
      const uint4 rv = *(const uint4*)((const char*)Rs + rsAddr0 + it * 4096);
      bf16x8 hb;
      #pragma unroll
      for (int e = 0; e < 4; ++e) {
        const unsigned d = ((const unsigned*)&rv)[e];
        float t0 = bflo(d) + l8[2 * e];
        float t1 = bfhi(d) + l8[2 * e + 1];
        t0 = t0 > 0.f ? t0 : 0.f;
        t1 = t1 > 0.f ? t1 : 0.f;
        hb[2 * e] = (__bf16)t0;
        hb[2 * e + 1] = (__bf16)t1;
      }
      *(bf16x8*)((char*)Hs + hsAddr0 + it * 4096) = hb;
    }
    __syncthreads();   // bar A: Hs ready, Rs consumed

    // ---- async stage next tile into Rs (lands by barB's vmcnt) ----
    if (jt < 15) {
      const int laneoff = (lane >> 5) * NH + (lane & 31) * 8;
      const __bf16* base = Rbb + (jt + 1) * (JT * NH);
      #pragma unroll
      for (int q = 0; q < 4; ++q) {
        const __bf16* src = base + (w * 4 + q) * 2 * NH + laneoff;
        gload_lds16(src, (char*)Rs + (w * 4 + q) * 1024);
      }
    }

    // ---- MFMA: wave computes 32j x 32k ----
    f32x4 acc[2][2];
    #pragma unroll
    for (int ja = 0; ja < 2; ++ja)
      #pragma unroll
      for (int kb = 0; kb < 2; ++kb) acc[ja][kb] = (f32x4){0.f, 0.f, 0.f, 0.f};
    #pragma unroll
    for (int ks8 = 0; ks8 < 8; ++ks8) {
      bf16x8 af[2];
      #pragma unroll
      for (int ja = 0; ja < 2; ++ja)
        af[ja] = *(const bf16x8*)((const char*)Hs + (ja * 16 + lr) * 512 + (((ks8 * 4 + lg) ^ (lr & 7)) << 4));
      #pragma unroll
      for (int ja = 0; ja < 2; ++ja)
        #pragma unroll
        for (int kb = 0; kb < 2; ++kb)
          acc[ja][kb] = __builtin_amdgcn_mfma_f32_16x16x32_bf16(af[ja], bfr[ks8][kb], acc[ja][kb], 0, 0, 0);
    }

    // ---- epilogue: relu(T+b2).W3 partial sums ----
    #pragma unroll
    for (int ja = 0; ja < 2; ++ja) {
      #pragma unroll
      for (int r = 0; r < 4; ++r) {
        const int k0 = w * 32 + lr;
        float t0 = acc[ja][0][r] + b2s[k0];
        float t1 = acc[ja][1][r] + b2s[k0 + 16];
        t0 = t0 > 0.f ? t0 : 0.f;
        t1 = t1 > 0.f ? t1 : 0.f;
        float s = fmaf(t0, W3s[k0], t1 * W3s[k0 + 16]);
        s += __shfl_xor(s, 1, 16);
        s += __shfl_xor(s, 2, 16);
        s += __shfl_xor(s, 4, 16);
        s += __shfl_xor(s, 8, 16);
        if (lr == 0) red[w][ja * 16 + lg * 4 + r] = s;
      }
    }
    asm volatile("s_waitcnt vmcnt(0)" ::: "memory");
    __syncthreads();   // bar B: red ready, Hs consumed, Rs(jt+1) landed

    if (tid < JT) {
      const float v = red[0][tid] + red[1][tid] + red[2][tid] + red[3][tid] + b3v;
      const float sg = 1.f / (1.f + __expf(-v));
      const int j = jt * JT + tid;
      ew[j] = adjs[j] * sg + ((j == i) ? 1.f : 0.f);
    }
  }
  __syncthreads();

  // ---- softmax over ew[0..511] ----
  float v0 = ew[tid], v1 = ew[tid + 256];
  float m = fmaxf(v0, v1);
  #pragma unroll
  for (int off = 1; off < 64; off <<= 1) m = fmaxf(m, __shfl_xor(m, off, 64));
  if (lane == 0) sred[w] = m;
  __syncthreads();
  m = fmaxf(fmaxf(sred[0], sred[1]), fmaxf(sred[2], sred[3]));
  const float e0 = __expf(v0 - m), e1 = __expf(v1 - m);
  float ssum = e0 + e1;
  #pragma unroll
  for (int off = 1; off < 64; off <<= 1) ssum += __shfl_xor(ssum, off, 64);
  if (lane == 0) sred[4 + w] = ssum;
  __syncthreads();
  const float inv = 1.f / (sred[4] + sred[5] + sred[6] + sred[7]);
  const float p0 = e0 * inv, p1 = e1 * inv;

  // split p into bf16 hi+lo, overlaid on ew region (p = hi + lo exactly)
  __bf16* ewh = (__bf16*)ew;      // [512] hi at bytes [0,1024)
  __bf16* ewl = ewh + NN;         // [512] lo at bytes [1024,2048)
  {
    const __bf16 h0 = (__bf16)p0;
    const __bf16 h1 = (__bf16)p1;
    ewh[tid] = h0;        ewl[tid] = (__bf16)(p0 - (float)h0);
    ewh[tid + 256] = h1;  ewl[tid + 256] = (__bf16)(p1 - (float)h1);
  }
  __syncthreads();

  // PV via MFMA: A row0 = p_hi, row1 = p_lo, rows 2-15 = 0; B = XWt slices.
  const char* ewb = (const char*)ew;
  const unsigned aoff = (lr == 1 ? 1024u : 0u) + lg * 16;
  const bool azero = (lr >= 2);
  f32x4 pacc[4];
  #pragma unroll
  for (int q = 0; q < 4; ++q) pacc[q] = (f32x4){0.f, 0.f, 0.f, 0.f};
  #pragma unroll
  for (int ks = 0; ks < 16; ++ks) {
    uint4 pa = *(const uint4*)(ewb + aoff + ks * 64);
    if (azero) { pa.x = 0; pa.y = 0; pa.z = 0; pa.w = 0; }
    const bf16x8 paf = __builtin_bit_cast(bf16x8, pa);
    #pragma unroll
    for (int q = 0; q < 4; ++q) {
      const int h = w * 64 + q * 16 + lr;
      const bf16x8 bv = *(const bf16x8*)(XWtb + h * NN + ks * 32 + lg * 8);
      pacc[q] = __builtin_amdgcn_mfma_f32_16x16x32_bf16(paf, bv, pacc[q], 0, 0, 0);
    }
  }
  if (lg == 0) {
    #pragma unroll
    for (int q = 0; q < 4; ++q)
      out[blk * NH + w * 64 + q * 16 + lr] = pacc[q][0] + pacc[q][1];
  }
}

extern "C" void kernel_launch(void* const* d_in, const int* in_sizes, int n_in,
                              void* d_out, int out_size, void* d_ws, size_t ws_size,
                              hipStream_t stream) {
  const float* x        = (const float*)d_in[0];
  const float* base_adj = (const float*)d_in[1];
  const float* W1       = (const float*)d_in[2];
  const float* b1       = (const float*)d_in[3];
  const float* W2       = (const float*)d_in[4];
  const float* b2       = (const float*)d_in[5];
  const float* W3       = (const float*)d_in[6];
  const float* b3       = (const float*)d_in[7];
  const float* Wg       = (const float*)d_in[8];
  const float* bg       = (const float*)d_in[9];

  float*  Lb    = (float*)d_ws;                       // [1024,256] f32
  __bf16* Rb16  = (__bf16*)(Lb + NB * NN * NH);       // [1024,256] bf16
  __bf16* XWt   = Rb16 + NB * NN * NH;                // [B][256 h][512 j] bf16
  __bf16* W2b   = XWt + NB * NH * NN;                 // [128,256] bf16
  float* outp = (float*)d_out;

  prep_kernel<<<384, 256, 0, stream>>>(x, W1, b1, Wg, bg, W2, Lb, Rb16, XWt, W2b);
  edge_kernel<<<NB * NN, 256, 0, stream>>>(base_adj, b2, W3, b3, Lb, Rb16, XWt, W2b, outp);
}